// Round 7
// baseline (248.781 us; speedup 1.0000x reference)
//
#include <hip/hip_runtime.h>
#include <math.h>

#define N_CH 128
#define NB_MAX 512          // nb <= 512 (n_nodes <= 16384; src/dst fit 14 bits)
#define BIN_CHUNK 2048
#define BIN_T 512

// ---------------------------------------------------------------------------
// block-wide exclusive scan over 512 ints via wave shuffles.
// wsums: LDS int[8]. Returns exclusive prefix.
// ---------------------------------------------------------------------------
__device__ __forceinline__ int block_excl_scan512(int v, int tid, int* wsums) {
    __syncthreads();                      // protect wsums reuse
    const int lane = tid & 63, w = tid >> 6;
    int inc = v;
    #pragma unroll
    for (int i = 1; i < 64; i <<= 1) {
        int t = __shfl_up(inc, i, 64);
        if (lane >= i) inc += t;
    }
    if (lane == 63) wsums[w] = inc;
    __syncthreads();
    if (w == 0) {
        int s = (lane < 8) ? wsums[lane] : 0;
        #pragma unroll
        for (int i = 1; i < 8; i <<= 1) {
            int t = __shfl_up(s, i, 64);
            if (lane >= i) s += t;
        }
        if (lane < 8) wsums[lane] = s;    // inclusive wave sums
    }
    __syncthreads();
    int base = (w > 0) ? wsums[w - 1] : 0;
    return base + inc - v;
}

// ---------------------------------------------------------------------------
// K0: blocks [0, nblk): per-chunk bucket histogram -> private row of
//     binCountPB (no atomics, no zero-init). Block nblk: V1/V2 transform.
// ---------------------------------------------------------------------------
__global__ __launch_bounds__(BIN_T) void preph_kernel(const float* __restrict__ W,
                                                      const int* __restrict__ dst,
                                                      float* __restrict__ V1,
                                                      float* __restrict__ V2,
                                                      int* __restrict__ binCountPB,
                                                      int n_edges, int nb, int nblk) {
    const int tid = threadIdx.x;
    if ((int)blockIdx.x == nblk) {
        for (int i = tid; i < N_CH * N_CH; i += BIN_T) {
            int k = i >> 7, o = i & 127;
            float w1 = W[o * 256 + k];
            float w2 = W[o * 256 + 128 + k];
            V1[i] = w1 - w2;
            V2[i] = w2;
        }
        return;
    }
    __shared__ int h[NB_MAX];
    for (int i = tid; i < nb; i += BIN_T) h[i] = 0;
    __syncthreads();
    const int base = blockIdx.x * BIN_CHUNK;
    const int cnt = min(BIN_CHUNK, n_edges - base);
    const int j0 = tid * 4;               // exactly one int4 per thread
    if (j0 + 3 < cnt) {
        int4 d = *(const int4*)(dst + base + j0);
        atomicAdd(&h[d.x >> 5], 1);
        atomicAdd(&h[d.y >> 5], 1);
        atomicAdd(&h[d.z >> 5], 1);
        atomicAdd(&h[d.w >> 5], 1);
    } else {
        for (int j = j0; j < cnt; ++j) atomicAdd(&h[dst[base + j] >> 5], 1);
    }
    __syncthreads();
    for (int i = tid; i < nb; i += BIN_T)
        binCountPB[blockIdx.x * nb + i] = h[i];
}

// ---------------------------------------------------------------------------
// K1: bbase — single block. Computes binOff[] (scan of bucket totals) and
// the per-(chunk,bucket) global write base table:
//   binBasePB[j*nb+b] = binOff[b] + sum_{j'<j} binCountPB[j'*nb+b]
// Bucket-per-lane: all loads/stores coalesced, O(nblk) iterations total.
// ---------------------------------------------------------------------------
__global__ __launch_bounds__(512) void bbase_kernel(const int* __restrict__ binCountPB,
                                                    int* __restrict__ binOff,
                                                    int* __restrict__ binBasePB,
                                                    int nb, int nblk, int n_edges) {
    __shared__ int wsums[8];
    const int tid = threadIdx.x;
    int tot = 0;
    if (tid < nb)
        for (int j = 0; j < nblk; ++j) tot += binCountPB[j * nb + tid];
    int off = block_excl_scan512(tot, tid, wsums);
    if (tid < nb) {
        binOff[tid] = off;
        int run = off;
        for (int j = 0; j < nblk; ++j) {
            binBasePB[j * nb + tid] = run;
            run += binCountPB[j * nb + tid];   // L2-hot re-read
        }
    }
    if (tid == 0) binOff[nb] = n_edges;
}

// ---------------------------------------------------------------------------
// K2: A = x @ V1 + bias (fp32), Bh = bf16(x @ V2). fp32 VALU GEMM.
// ---------------------------------------------------------------------------
__global__ __launch_bounds__(256) void gemm_kernel(const float* __restrict__ x,
                                                   const float* __restrict__ V1,
                                                   const float* __restrict__ V2,
                                                   const float* __restrict__ bias,
                                                   float* __restrict__ A,
                                                   unsigned short* __restrict__ Bh,
                                                   int n_nodes) {
    __shared__ float xs[32][N_CH];      // 16 KB
    const int n0 = blockIdx.x * 32;
    const int tid = threadIdx.x;

    if (n0 + 32 <= n_nodes) {
        const float4* xg = (const float4*)(x + (size_t)n0 * N_CH);
        float4* xsv = (float4*)&xs[0][0];
        #pragma unroll
        for (int i = 0; i < 4; ++i) xsv[tid + i * 256] = xg[tid + i * 256];
    } else {
        for (int i = tid; i < 32 * N_CH; i += 256) {
            int n = n0 + (i >> 7);
            (&xs[0][0])[i] = (n < n_nodes) ? x[(size_t)n * N_CH + (i & 127)] : 0.f;
        }
    }
    __syncthreads();

    const int o  = tid & 127;
    const int nh = tid >> 7;            // 0 or 1
    const float bo = bias[o];
    float acc1[16], acc2[16];
    #pragma unroll
    for (int i = 0; i < 16; ++i) { acc1[i] = 0.f; acc2[i] = 0.f; }

    const float* xrow = &xs[nh * 16][0];
    for (int k4 = 0; k4 < N_CH; k4 += 4) {
        float w1[4], w2[4];
        #pragma unroll
        for (int j = 0; j < 4; ++j) {
            w1[j] = V1[(k4 + j) * N_CH + o];
            w2[j] = V2[(k4 + j) * N_CH + o];
        }
        #pragma unroll
        for (int i = 0; i < 16; ++i) {
            float4 xv = *(const float4*)&xrow[i * N_CH + k4];
            acc1[i] = fmaf(xv.x, w1[0], acc1[i]); acc2[i] = fmaf(xv.x, w2[0], acc2[i]);
            acc1[i] = fmaf(xv.y, w1[1], acc1[i]); acc2[i] = fmaf(xv.y, w2[1], acc2[i]);
            acc1[i] = fmaf(xv.z, w1[2], acc1[i]); acc2[i] = fmaf(xv.z, w2[2], acc2[i]);
            acc1[i] = fmaf(xv.w, w1[3], acc1[i]); acc2[i] = fmaf(xv.w, w2[3], acc2[i]);
        }
    }

    #pragma unroll
    for (int i = 0; i < 16; ++i) {
        int n = n0 + nh * 16 + i;
        if (n < n_nodes) {
            A[(size_t)n * N_CH + o] = acc1[i] + bo;
            unsigned int bits = __float_as_uint(acc2[i]);
            unsigned int r = (bits + 0x7FFFu + ((bits >> 16) & 1u)) >> 16;
            Bh[(size_t)n * N_CH + o] = (unsigned short)r;
        }
    }
}

// ---------------------------------------------------------------------------
// K3: bin scatter. Reads its own precomputed write-base row (coalesced),
// counting-sorts its 2048-edge chunk in LDS, writes packed (dst<<14|src)
// in bucket-ordered runs. Fully atomic-free globally, deterministic.
// ---------------------------------------------------------------------------
__global__ __launch_bounds__(BIN_T) void bin_kernel(const int* __restrict__ src,
                                                    const int* __restrict__ dst,
                                                    const int* __restrict__ binCountPB,
                                                    const int* __restrict__ binBasePB,
                                                    unsigned int* __restrict__ binned,
                                                    int n_edges, int nb) {
    __shared__ unsigned int lpk[BIN_CHUNK];        // 8 KB sorted chunk
    __shared__ int gbase[NB_MAX];                  // global write base per bucket
    __shared__ int lexcl[NB_MAX];                  // local sorted offset
    __shared__ int lcur[NB_MAX];
    __shared__ int wsums[8];

    const int tid = threadIdx.x;
    const int bid = blockIdx.x;
    const int base = bid * BIN_CHUNK;
    const int cnt = min(BIN_CHUNK, n_edges - base);

    // own-chunk bucket counts + local exclusive scan + global base row
    int own = (tid < nb) ? binCountPB[bid * nb + tid] : 0;
    int offO = block_excl_scan512(own, tid, wsums);
    if (tid < nb) {
        lexcl[tid] = offO;
        lcur[tid] = offO;
        gbase[tid] = binBasePB[bid * nb + tid];
    }

    // load + pack (one int4 per thread)
    unsigned int vreg[4];
    int nloc = 0;
    const int j0 = tid * 4;
    if (j0 + 3 < cnt) {
        int4 s4 = *(const int4*)(src + base + j0);
        int4 d4 = *(const int4*)(dst + base + j0);
        vreg[nloc++] = ((unsigned int)d4.x << 14) | (unsigned int)s4.x;
        vreg[nloc++] = ((unsigned int)d4.y << 14) | (unsigned int)s4.y;
        vreg[nloc++] = ((unsigned int)d4.z << 14) | (unsigned int)s4.z;
        vreg[nloc++] = ((unsigned int)d4.w << 14) | (unsigned int)s4.w;
    } else {
        for (int j = j0; j < cnt; ++j)
            vreg[nloc++] = ((unsigned int)dst[base + j] << 14) | (unsigned int)src[base + j];
    }
    __syncthreads();                               // lexcl/lcur ready

    // local counting-sort scatter into LDS
    for (int k = 0; k < nloc; ++k) {
        int b = (int)(vreg[k] >> 19);              // bucket = dst >> 5
        int p = atomicAdd(&lcur[b], 1);
        lpk[p] = vreg[k];
    }
    __syncthreads();

    // ordered write-out (runs of same bucket are consecutive)
    for (int i = tid; i < cnt; i += BIN_T) {
        unsigned int w = lpk[i];
        int b = (int)(w >> 19);
        binned[gbase[b] + (i - lexcl[b])] = w;
    }
}

// ---------------------------------------------------------------------------
// K4: per-bucket CSR build (32 nodes/bucket). Per-wave hist + cursors to cut
// LDS same-address atomic serialization 4x. eidx scatter stays in the
// bucket's contiguous window; offsets[] emitted directly.
// ---------------------------------------------------------------------------
__global__ __launch_bounds__(256) void build_kernel(const unsigned int* __restrict__ binned,
                                                    const int* __restrict__ binOff,
                                                    int* __restrict__ offsets,
                                                    int* __restrict__ eidx,
                                                    int n_nodes, int nb) {
    __shared__ int whist[4][32];     // per-wave node counts -> later cursors
    __shared__ int lexcl[33];
    const int b = blockIdx.x;
    const int tid = threadIdx.x;
    const int w = tid >> 6;
    const int rbeg = binOff[b], rend = binOff[b + 1];

    if (tid < 128) ((int*)whist)[tid] = 0;
    __syncthreads();
    for (int i = rbeg + tid; i < rend; i += 256)
        atomicAdd(&whist[w][(binned[i] >> 14) & 31], 1);
    __syncthreads();
    if (tid == 0) {
        int s = 0;
        #pragma unroll
        for (int k = 0; k < 32; ++k) {
            lexcl[k] = s;
            s += whist[0][k] + whist[1][k] + whist[2][k] + whist[3][k];
        }
        lexcl[32] = s;
    }
    __syncthreads();
    if (tid < 32) {
        int basec = lexcl[tid];
        #pragma unroll
        for (int ww = 0; ww < 4; ++ww) {
            int c = whist[ww][tid];
            whist[ww][tid] = basec;   // becomes this wave's cursor for node tid
            basec += c;
        }
        int n = b * 32 + tid;
        if (n < n_nodes) offsets[n] = rbeg + lexcl[tid];
    }
    if (b == nb - 1 && tid == 0) offsets[n_nodes] = rend;
    __syncthreads();
    for (int i = rbeg + tid; i < rend; i += 256) {
        unsigned int wd = binned[i];
        int v = (int)((wd >> 14) & 31);
        int r = atomicAdd(&whist[w][v], 1);
        eidx[rbeg + r] = (int)(wd & 16383u);
    }
}

// ---------------------------------------------------------------------------
// K5: per-node gather-max. One WAVE per node, 4 nodes/block. Lane l covers
// channels 2l,2l+1 (bf16 pair). Wave-synchronous LDS staging.
// ---------------------------------------------------------------------------
__global__ __launch_bounds__(256) void gather_kernel(
        const float* __restrict__ A,
        const unsigned int* __restrict__ Bh2,   // n_nodes x 64 uints
        const int* __restrict__ offsets,
        const int* __restrict__ eidx,
        float* __restrict__ out,
        int n_nodes) {
    __shared__ int sidx[4][64];
    const int g = threadIdx.x >> 6;
    const int l = threadIdx.x & 63;
    const int n = blockIdx.x * 4 + g;
    if (n >= n_nodes) return;
    const int beg = offsets[n], end = offsets[n + 1];

    float mlo[8], mhi[8];
    #pragma unroll
    for (int i = 0; i < 8; ++i) { mlo[i] = -INFINITY; mhi[i] = -INFINITY; }

    for (int base = beg; base < end; base += 64) {
        int p = base + l;
        if (p < end) sidx[g][l] = eidx[p];
        int cnt = min(64, end - base);
        int q = 0;
        for (; q + 8 <= cnt; q += 8) {
            unsigned int w[8];
            #pragma unroll
            for (int i = 0; i < 8; ++i)
                w[i] = Bh2[(size_t)sidx[g][q + i] * 64 + l];
            #pragma unroll
            for (int i = 0; i < 8; ++i) {
                mlo[i] = fmaxf(mlo[i], __uint_as_float(w[i] << 16));
                mhi[i] = fmaxf(mhi[i], __uint_as_float(w[i] & 0xFFFF0000u));
            }
        }
        for (; q < cnt; ++q) {
            unsigned int w = Bh2[(size_t)sidx[g][q] * 64 + l];
            mlo[0] = fmaxf(mlo[0], __uint_as_float(w << 16));
            mhi[0] = fmaxf(mhi[0], __uint_as_float(w & 0xFFFF0000u));
        }
    }

    float lo = mlo[0], hi = mhi[0];
    #pragma unroll
    for (int i = 1; i < 8; ++i) { lo = fmaxf(lo, mlo[i]); hi = fmaxf(hi, mhi[i]); }

    float2 r = make_float2(0.f, 0.f);
    if (end > beg) {
        float2 a = *(const float2*)(A + (size_t)n * N_CH + 2 * l);
        r.x = a.x + lo;
        r.y = a.y + hi;
    }
    *(float2*)(out + (size_t)n * N_CH + 2 * l) = r;
}

// ---------------------------------------------------------------------------
extern "C" void kernel_launch(void* const* d_in, const int* in_sizes, int n_in,
                              void* d_out, int out_size, void* d_ws, size_t ws_size,
                              hipStream_t stream) {
    const float* x = (const float*)d_in[0];
    const float* W = (const float*)d_in[1];
    const float* b = (const float*)d_in[2];
    const int*   ei = (const int*)d_in[3];

    const int n_nodes = in_sizes[0] / N_CH;   // 10000
    const int n_edges = in_sizes[3] / 2;      // 640000
    const int nb = (n_nodes + 31) >> 5;       // 313 buckets of 32 nodes
    const int* src = ei;
    const int* dst = ei + n_edges;
    float* out = (float*)d_out;

    char* ws = (char*)d_ws;
    size_t off = 0;
    auto alloc = [&](size_t bytes) -> void* {
        void* p = ws + off;
        off += (bytes + 255) & ~(size_t)255;
        return p;
    };
    const int nblk = (n_edges + BIN_CHUNK - 1) / BIN_CHUNK;   // 313

    float* V1          = (float*)alloc((size_t)N_CH * N_CH * 4);
    float* V2          = (float*)alloc((size_t)N_CH * N_CH * 4);
    float* A           = (float*)alloc((size_t)n_nodes * N_CH * 4);
    unsigned short* Bh = (unsigned short*)alloc((size_t)n_nodes * N_CH * 2);
    int* binCountPB    = (int*)alloc((size_t)nblk * nb * 4);
    int* binBasePB     = (int*)alloc((size_t)nblk * nb * 4);
    int* binOff        = (int*)alloc((size_t)(nb + 1) * 4);
    unsigned int* binned = (unsigned int*)alloc((size_t)n_edges * 4);
    int* offsets       = (int*)alloc((size_t)(n_nodes + 1) * 4);
    int* eidx          = (int*)alloc((size_t)n_edges * 4);
    (void)ws_size; (void)n_in; (void)out_size;

    preph_kernel<<<nblk + 1, BIN_T, 0, stream>>>(W, dst, V1, V2, binCountPB, n_edges, nb, nblk);
    gemm_kernel <<<(n_nodes + 31) / 32, 256, 0, stream>>>(x, V1, V2, b, A, Bh, n_nodes);
    bbase_kernel<<<1, 512, 0, stream>>>(binCountPB, binOff, binBasePB, nb, nblk, n_edges);
    bin_kernel  <<<nblk, BIN_T, 0, stream>>>(src, dst, binCountPB, binBasePB, binned, n_edges, nb);
    build_kernel<<<nb, 256, 0, stream>>>(binned, binOff, offsets, eidx, n_nodes, nb);
    gather_kernel<<<(n_nodes + 3) / 4, 256, 0, stream>>>(A, (const unsigned int*)Bh, offsets, eidx, out, n_nodes);
}

// Round 8
// 148.905 us; speedup vs baseline: 1.6707x; 1.6707x over previous
//
#include <hip/hip_runtime.h>
#include <math.h>

#define N_CH 128
#define NB_MAX 512          // nb <= 512 (n_nodes <= 16384; src/dst fit 14 bits)
#define BIN_CHUNK 4096
#define BIN_T 512

// ---------------------------------------------------------------------------
// block-wide exclusive scan over 512 ints via wave shuffles.
// wsums: LDS int[8]. Returns exclusive prefix.
// ---------------------------------------------------------------------------
__device__ __forceinline__ int block_excl_scan512(int v, int tid, int* wsums) {
    __syncthreads();                      // protect wsums reuse
    const int lane = tid & 63, w = tid >> 6;
    int inc = v;
    #pragma unroll
    for (int i = 1; i < 64; i <<= 1) {
        int t = __shfl_up(inc, i, 64);
        if (lane >= i) inc += t;
    }
    if (lane == 63) wsums[w] = inc;
    __syncthreads();
    if (w == 0) {
        int s = (lane < 8) ? wsums[lane] : 0;
        #pragma unroll
        for (int i = 1; i < 8; i <<= 1) {
            int t = __shfl_up(s, i, 64);
            if (lane >= i) s += t;
        }
        if (lane < 8) wsums[lane] = s;    // inclusive wave sums
    }
    __syncthreads();
    int base = (w > 0) ? wsums[w - 1] : 0;
    return base + inc - v;
}

// ---------------------------------------------------------------------------
// K0: blocks [0, nblk): LDS bucket hist of chunk -> global atomicAdd into
//     binCount (zeroed by hipMemsetAsync). Block nblk: V1/V2 transform.
// ---------------------------------------------------------------------------
__global__ __launch_bounds__(BIN_T) void preph_kernel(const float* __restrict__ W,
                                                      const int* __restrict__ dst,
                                                      float* __restrict__ V1,
                                                      float* __restrict__ V2,
                                                      int* __restrict__ binCount,
                                                      int n_edges, int nb, int nblk) {
    const int tid = threadIdx.x;
    if ((int)blockIdx.x == nblk) {
        for (int i = tid; i < N_CH * N_CH; i += BIN_T) {
            int k = i >> 7, o = i & 127;
            float w1 = W[o * 256 + k];
            float w2 = W[o * 256 + 128 + k];
            V1[i] = w1 - w2;
            V2[i] = w2;
        }
        return;
    }
    __shared__ int h[NB_MAX];
    for (int i = tid; i < nb; i += BIN_T) h[i] = 0;
    __syncthreads();
    const int base = blockIdx.x * BIN_CHUNK;
    const int cnt = min(BIN_CHUNK, n_edges - base);
    #pragma unroll
    for (int u = 0; u < 2; ++u) {
        const int j0 = (tid + u * BIN_T) * 4;
        if (j0 + 3 < cnt) {
            int4 d = *(const int4*)(dst + base + j0);
            atomicAdd(&h[d.x >> 5], 1);
            atomicAdd(&h[d.y >> 5], 1);
            atomicAdd(&h[d.z >> 5], 1);
            atomicAdd(&h[d.w >> 5], 1);
        } else {
            for (int j = j0; j < min(cnt, j0 + 4); ++j)
                atomicAdd(&h[dst[base + j] >> 5], 1);
        }
    }
    __syncthreads();
    for (int i = tid; i < nb; i += BIN_T)
        if (h[i]) atomicAdd(&binCount[i], h[i]);
}

// ---------------------------------------------------------------------------
// K1: A = x @ V1 + bias (fp32), Bh = bf16(x @ V2). fp32 VALU GEMM.
// ---------------------------------------------------------------------------
__global__ __launch_bounds__(256) void gemm_kernel(const float* __restrict__ x,
                                                   const float* __restrict__ V1,
                                                   const float* __restrict__ V2,
                                                   const float* __restrict__ bias,
                                                   float* __restrict__ A,
                                                   unsigned short* __restrict__ Bh,
                                                   int n_nodes) {
    __shared__ float xs[32][N_CH];      // 16 KB
    const int n0 = blockIdx.x * 32;
    const int tid = threadIdx.x;

    if (n0 + 32 <= n_nodes) {
        const float4* xg = (const float4*)(x + (size_t)n0 * N_CH);
        float4* xsv = (float4*)&xs[0][0];
        #pragma unroll
        for (int i = 0; i < 4; ++i) xsv[tid + i * 256] = xg[tid + i * 256];
    } else {
        for (int i = tid; i < 32 * N_CH; i += 256) {
            int n = n0 + (i >> 7);
            (&xs[0][0])[i] = (n < n_nodes) ? x[(size_t)n * N_CH + (i & 127)] : 0.f;
        }
    }
    __syncthreads();

    const int o  = tid & 127;
    const int nh = tid >> 7;            // 0 or 1
    const float bo = bias[o];
    float acc1[16], acc2[16];
    #pragma unroll
    for (int i = 0; i < 16; ++i) { acc1[i] = 0.f; acc2[i] = 0.f; }

    const float* xrow = &xs[nh * 16][0];
    for (int k4 = 0; k4 < N_CH; k4 += 4) {
        float w1[4], w2[4];
        #pragma unroll
        for (int j = 0; j < 4; ++j) {
            w1[j] = V1[(k4 + j) * N_CH + o];
            w2[j] = V2[(k4 + j) * N_CH + o];
        }
        #pragma unroll
        for (int i = 0; i < 16; ++i) {
            float4 xv = *(const float4*)&xrow[i * N_CH + k4];
            acc1[i] = fmaf(xv.x, w1[0], acc1[i]); acc2[i] = fmaf(xv.x, w2[0], acc2[i]);
            acc1[i] = fmaf(xv.y, w1[1], acc1[i]); acc2[i] = fmaf(xv.y, w2[1], acc2[i]);
            acc1[i] = fmaf(xv.z, w1[2], acc1[i]); acc2[i] = fmaf(xv.z, w2[2], acc2[i]);
            acc1[i] = fmaf(xv.w, w1[3], acc1[i]); acc2[i] = fmaf(xv.w, w2[3], acc2[i]);
        }
    }

    #pragma unroll
    for (int i = 0; i < 16; ++i) {
        int n = n0 + nh * 16 + i;
        if (n < n_nodes) {
            A[(size_t)n * N_CH + o] = acc1[i] + bo;
            unsigned int bits = __float_as_uint(acc2[i]);
            unsigned int r = (bits + 0x7FFFu + ((bits >> 16) & 1u)) >> 16;
            Bh[(size_t)n * N_CH + o] = (unsigned short)r;
        }
    }
}

// ---------------------------------------------------------------------------
// K2: exclusive scan over nb bucket counts -> binOff[nb+1], binCursor copy.
// Single block, shuffle scan (registers, no long global loops).
// ---------------------------------------------------------------------------
__global__ __launch_bounds__(512) void bscan_kernel(const int* __restrict__ binCount,
                                                    int* __restrict__ binOff,
                                                    int* __restrict__ binCursor,
                                                    int nb, int n_edges) {
    __shared__ int wsums[8];
    const int tid = threadIdx.x;
    int v = (tid < nb) ? binCount[tid] : 0;
    int excl = block_excl_scan512(v, tid, wsums);
    if (tid < nb) {
        binOff[tid] = excl;
        binCursor[tid] = excl;
    }
    if (tid == 0) binOff[nb] = n_edges;
}

// ---------------------------------------------------------------------------
// K3: bin scatter (r4-proven): LDS hist of own chunk, shuffle scan, local
// counting-sort in LDS, per-bucket global range reservation via atomicAdd
// on binCursor (order within bucket non-deterministic — max is commutative),
// bucket-ordered coalesced-run write-out of packed (dst<<14|src).
// ---------------------------------------------------------------------------
__global__ __launch_bounds__(BIN_T) void bin_kernel(const int* __restrict__ src,
                                                    const int* __restrict__ dst,
                                                    int* __restrict__ binCursor,
                                                    unsigned int* __restrict__ binned,
                                                    int n_edges, int nb) {
    __shared__ unsigned int lpk[BIN_CHUNK];        // 16 KB sorted chunk
    __shared__ int lhist[NB_MAX], lexcl[NB_MAX], lcur[NB_MAX], gbase[NB_MAX];
    __shared__ int wsums[8];

    const int tid = threadIdx.x;
    const int base = blockIdx.x * BIN_CHUNK;
    const int cnt = min(BIN_CHUNK, n_edges - base);

    for (int i = tid; i < nb; i += BIN_T) lhist[i] = 0;
    __syncthreads();

    // load + pack, 8 edges (2 int4 pairs) per thread; count into LDS hist
    unsigned int vreg[8];
    int nloc = 0;
    #pragma unroll
    for (int u = 0; u < 2; ++u) {
        const int j0 = (tid + u * BIN_T) * 4;
        if (j0 + 3 < cnt) {
            int4 s4 = *(const int4*)(src + base + j0);
            int4 d4 = *(const int4*)(dst + base + j0);
            vreg[nloc++] = ((unsigned int)d4.x << 14) | (unsigned int)s4.x;
            vreg[nloc++] = ((unsigned int)d4.y << 14) | (unsigned int)s4.y;
            vreg[nloc++] = ((unsigned int)d4.z << 14) | (unsigned int)s4.z;
            vreg[nloc++] = ((unsigned int)d4.w << 14) | (unsigned int)s4.w;
        } else {
            for (int j = j0; j < min(cnt, j0 + 4); ++j)
                vreg[nloc++] = ((unsigned int)dst[base + j] << 14) | (unsigned int)src[base + j];
        }
    }
    for (int k = 0; k < nloc; ++k)
        atomicAdd(&lhist[vreg[k] >> 19], 1);
    __syncthreads();

    // local exclusive scan of bucket counts + global range reservation
    int own = (tid < nb) ? lhist[tid] : 0;
    int offO = block_excl_scan512(own, tid, wsums);
    if (tid < nb) {
        lexcl[tid] = offO;
        lcur[tid] = offO;
        if (own) gbase[tid] = atomicAdd(&binCursor[tid], own);
    }
    __syncthreads();

    // local counting-sort scatter into LDS
    for (int k = 0; k < nloc; ++k) {
        int b = (int)(vreg[k] >> 19);              // bucket = dst >> 5
        int p = atomicAdd(&lcur[b], 1);
        lpk[p] = vreg[k];
    }
    __syncthreads();

    // ordered write-out (runs of same bucket are consecutive)
    for (int i = tid; i < cnt; i += BIN_T) {
        unsigned int w = lpk[i];
        int b = (int)(w >> 19);
        binned[gbase[b] + (i - lexcl[b])] = w;
    }
}

// ---------------------------------------------------------------------------
// K4: per-bucket CSR build (32 nodes/bucket). Per-wave hist + cursors to cut
// LDS same-address atomic serialization 4x. eidx scatter stays in the
// bucket's contiguous window; offsets[] emitted directly.
// ---------------------------------------------------------------------------
__global__ __launch_bounds__(256) void build_kernel(const unsigned int* __restrict__ binned,
                                                    const int* __restrict__ binOff,
                                                    int* __restrict__ offsets,
                                                    int* __restrict__ eidx,
                                                    int n_nodes, int nb) {
    __shared__ int whist[4][32];     // per-wave node counts -> later cursors
    __shared__ int lexcl[33];
    const int b = blockIdx.x;
    const int tid = threadIdx.x;
    const int w = tid >> 6;
    const int rbeg = binOff[b], rend = binOff[b + 1];

    if (tid < 128) ((int*)whist)[tid] = 0;
    __syncthreads();
    for (int i = rbeg + tid; i < rend; i += 256)
        atomicAdd(&whist[w][(binned[i] >> 14) & 31], 1);
    __syncthreads();
    if (tid == 0) {
        int s = 0;
        #pragma unroll
        for (int k = 0; k < 32; ++k) {
            lexcl[k] = s;
            s += whist[0][k] + whist[1][k] + whist[2][k] + whist[3][k];
        }
        lexcl[32] = s;
    }
    __syncthreads();
    if (tid < 32) {
        int basec = lexcl[tid];
        #pragma unroll
        for (int ww = 0; ww < 4; ++ww) {
            int c = whist[ww][tid];
            whist[ww][tid] = basec;   // becomes this wave's cursor for node tid
            basec += c;
        }
        int n = b * 32 + tid;
        if (n < n_nodes) offsets[n] = rbeg + lexcl[tid];
    }
    if (b == nb - 1 && tid == 0) offsets[n_nodes] = rend;
    __syncthreads();
    for (int i = rbeg + tid; i < rend; i += 256) {
        unsigned int wd = binned[i];
        int v = (int)((wd >> 14) & 31);
        int r = atomicAdd(&whist[w][v], 1);
        eidx[rbeg + r] = (int)(wd & 16383u);
    }
}

// ---------------------------------------------------------------------------
// K5: per-node gather-max. One WAVE per node, 4 nodes/block. Lane l covers
// channels 2l,2l+1 (bf16 pair). Wave-synchronous LDS staging.
// ---------------------------------------------------------------------------
__global__ __launch_bounds__(256) void gather_kernel(
        const float* __restrict__ A,
        const unsigned int* __restrict__ Bh2,   // n_nodes x 64 uints
        const int* __restrict__ offsets,
        const int* __restrict__ eidx,
        float* __restrict__ out,
        int n_nodes) {
    __shared__ int sidx[4][64];
    const int g = threadIdx.x >> 6;
    const int l = threadIdx.x & 63;
    const int n = blockIdx.x * 4 + g;
    if (n >= n_nodes) return;
    const int beg = offsets[n], end = offsets[n + 1];

    float mlo[8], mhi[8];
    #pragma unroll
    for (int i = 0; i < 8; ++i) { mlo[i] = -INFINITY; mhi[i] = -INFINITY; }

    for (int base = beg; base < end; base += 64) {
        int p = base + l;
        if (p < end) sidx[g][l] = eidx[p];
        int cnt = min(64, end - base);
        int q = 0;
        for (; q + 8 <= cnt; q += 8) {
            unsigned int w[8];
            #pragma unroll
            for (int i = 0; i < 8; ++i)
                w[i] = Bh2[(size_t)sidx[g][q + i] * 64 + l];
            #pragma unroll
            for (int i = 0; i < 8; ++i) {
                mlo[i] = fmaxf(mlo[i], __uint_as_float(w[i] << 16));
                mhi[i] = fmaxf(mhi[i], __uint_as_float(w[i] & 0xFFFF0000u));
            }
        }
        for (; q < cnt; ++q) {
            unsigned int w = Bh2[(size_t)sidx[g][q] * 64 + l];
            mlo[0] = fmaxf(mlo[0], __uint_as_float(w << 16));
            mhi[0] = fmaxf(mhi[0], __uint_as_float(w & 0xFFFF0000u));
        }
    }

    float lo = mlo[0], hi = mhi[0];
    #pragma unroll
    for (int i = 1; i < 8; ++i) { lo = fmaxf(lo, mlo[i]); hi = fmaxf(hi, mhi[i]); }

    float2 r = make_float2(0.f, 0.f);
    if (end > beg) {
        float2 a = *(const float2*)(A + (size_t)n * N_CH + 2 * l);
        r.x = a.x + lo;
        r.y = a.y + hi;
    }
    *(float2*)(out + (size_t)n * N_CH + 2 * l) = r;
}

// ---------------------------------------------------------------------------
extern "C" void kernel_launch(void* const* d_in, const int* in_sizes, int n_in,
                              void* d_out, int out_size, void* d_ws, size_t ws_size,
                              hipStream_t stream) {
    const float* x = (const float*)d_in[0];
    const float* W = (const float*)d_in[1];
    const float* b = (const float*)d_in[2];
    const int*   ei = (const int*)d_in[3];

    const int n_nodes = in_sizes[0] / N_CH;   // 10000
    const int n_edges = in_sizes[3] / 2;      // 640000
    const int nb = (n_nodes + 31) >> 5;       // 313 buckets of 32 nodes
    const int* src = ei;
    const int* dst = ei + n_edges;
    float* out = (float*)d_out;

    char* ws = (char*)d_ws;
    size_t off = 0;
    auto alloc = [&](size_t bytes) -> void* {
        void* p = ws + off;
        off += (bytes + 255) & ~(size_t)255;
        return p;
    };
    const int nblk = (n_edges + BIN_CHUNK - 1) / BIN_CHUNK;   // 157

    float* V1          = (float*)alloc((size_t)N_CH * N_CH * 4);
    float* V2          = (float*)alloc((size_t)N_CH * N_CH * 4);
    float* A           = (float*)alloc((size_t)n_nodes * N_CH * 4);
    unsigned short* Bh = (unsigned short*)alloc((size_t)n_nodes * N_CH * 2);
    int* binCount      = (int*)alloc((size_t)nb * 4);
    int* binOff        = (int*)alloc((size_t)(nb + 1) * 4);
    int* binCursor     = (int*)alloc((size_t)nb * 4);
    unsigned int* binned = (unsigned int*)alloc((size_t)n_edges * 4);
    int* offsets       = (int*)alloc((size_t)(n_nodes + 1) * 4);
    int* eidx          = (int*)alloc((size_t)n_edges * 4);
    (void)ws_size; (void)n_in; (void)out_size;

    hipMemsetAsync(binCount, 0, (size_t)nb * 4, stream);
    preph_kernel<<<nblk + 1, BIN_T, 0, stream>>>(W, dst, V1, V2, binCount, n_edges, nb, nblk);
    gemm_kernel <<<(n_nodes + 31) / 32, 256, 0, stream>>>(x, V1, V2, b, A, Bh, n_nodes);
    bscan_kernel<<<1, 512, 0, stream>>>(binCount, binOff, binCursor, nb, n_edges);
    bin_kernel  <<<nblk, BIN_T, 0, stream>>>(src, dst, binCursor, binned, n_edges, nb);
    build_kernel<<<nb, 256, 0, stream>>>(binned, binOff, offsets, eidx, n_nodes, nb);
    gather_kernel<<<(n_nodes + 3) / 4, 256, 0, stream>>>(A, (const unsigned int*)Bh, offsets, eidx, out, n_nodes);
}